// Round 4
// baseline (184.259 us; speedup 1.0000x reference)
//
#include <hip/hip_runtime.h>
#include <hip/hip_bf16.h>

// LPLayer: e = x@W^T + b; lp = relu(tanh(e@e^T)); nf = lp@e / N
// B=8, N=2048, C_IN=128, D(C_OUT)=64. All I/O fp32.
// d_out (float) = [nf (8*2048*64)] ++ [lp (8*2048*2048)]
//
// R4 structure: barrier-free fused j-loop.
//   - Gram/PV B-operands read straight from L2-resident e (per-XCD batch pin).
//   - lp stored direct from C-layout regs (4 full 128B lines per store instr).
//   - sLp LDS used ONLY for the same-wave C->A layout transform (no barrier).

#define B_    8
#define N_    2048
#define D_    64
#define CIN_  128

typedef __bf16 bf16x8 __attribute__((ext_vector_type(8)));
typedef float f32x4  __attribute__((ext_vector_type(4)));
typedef float f32x16 __attribute__((ext_vector_type(16)));

union FragU { uint4 u; bf16x8 f; };

static __device__ __forceinline__ bf16x8 ld_frag(const __hip_bfloat16* p) {
    FragU fu; fu.u = *reinterpret_cast<const uint4*>(p); return fu.f;
}

// Split 8 consecutive fp32 into hi/lo bf16x8 (hi = RTN(v), lo = RTN(v - hi)).
static __device__ __forceinline__ void split8(const float* p, bf16x8& hi, bf16x8& lo) {
    const float4 a = *reinterpret_cast<const float4*>(p);
    const float4 b = *reinterpret_cast<const float4*>(p + 4);
    const float v[8] = {a.x, a.y, a.z, a.w, b.x, b.y, b.z, b.w};
#pragma unroll
    for (int i = 0; i < 8; i++) {
        const __bf16 h = (__bf16)v[i];
        hi[i] = h;
        lo[i] = (__bf16)(v[i] - (float)h);
    }
}

// ---------------------------------------------------------------------------
// Kernel 0: pre-split W (fp32 [64][128]) into whi/wlo bf16 [64][128].
// ---------------------------------------------------------------------------
__global__ __launch_bounds__(256) void wsplit_kernel(
    const float* __restrict__ W,
    __hip_bfloat16* __restrict__ whi,
    __hip_bfloat16* __restrict__ wlo)
{
    const int tid = threadIdx.x;
#pragma unroll
    for (int k = 0; k < 8; k++) {
        const float4 v = reinterpret_cast<const float4*>(W)[tid * 8 + k];
        const int idx = tid * 32 + k * 4;
        const float vv[4] = {v.x, v.y, v.z, v.w};
#pragma unroll
        for (int j = 0; j < 4; j++) {
            const __hip_bfloat16 h = __float2bfloat16(vv[j]);
            whi[idx + j] = h;
            wlo[idx + j] = __float2bfloat16(vv[j] - __bfloat162float(h));
        }
    }
}

// ---------------------------------------------------------------------------
// Kernel 1: e = x @ W^T + b, emit e_hi/e_lo (bf16 split) + e_hiT ([B][64][N]).
// Grid 256 x 256 thr (4 waves x 16 rows). Split-MFMA: xh*wh + xh*wl + xl*wh.
// Epilogue stages through LDS for fully coalesced 16B stores (incl. transpose).
// ---------------------------------------------------------------------------
__global__ __launch_bounds__(256) void ex_kernel(
    const float* __restrict__ x,
    const __hip_bfloat16* __restrict__ whi,
    const __hip_bfloat16* __restrict__ wlo,
    const float* __restrict__ bias,
    __hip_bfloat16* __restrict__ e_hi,
    __hip_bfloat16* __restrict__ e_lo,
    __hip_bfloat16* __restrict__ e_hiT)
{
    __shared__ __align__(16) __hip_bfloat16 sEh[64 * 72];
    __shared__ __align__(16) __hip_bfloat16 sEl[64 * 72];
    __shared__ __align__(16) __hip_bfloat16 sEt[64 * 72];   // [chan][row]

    const int tid  = threadIdx.x;
    const int w    = tid >> 6;
    const int lane = tid & 63;
    const int quad = lane >> 4;
    const int l16  = lane & 15;
    const int gr0  = blockIdx.x * 64;            // 64 rows/block
    const int m0   = gr0 + w * 16;

    const float* xrow = x + (size_t)(m0 + l16) * CIN_;
    bf16x8 ah[4], al[4];
#pragma unroll
    for (int ks = 0; ks < 4; ks++)
        split8(xrow + ks * 32 + quad * 8, ah[ks], al[ks]);

    f32x4 acc[4];
#pragma unroll
    for (int nt = 0; nt < 4; nt++) acc[nt] = f32x4{0.f, 0.f, 0.f, 0.f};

#pragma unroll
    for (int ks = 0; ks < 4; ks++) {
#pragma unroll
        for (int nt = 0; nt < 4; nt++) {
            const bf16x8 wh = ld_frag(whi + (nt * 16 + l16) * CIN_ + ks * 32 + quad * 8);
            const bf16x8 wl = ld_frag(wlo + (nt * 16 + l16) * CIN_ + ks * 32 + quad * 8);
            acc[nt] = __builtin_amdgcn_mfma_f32_16x16x32_bf16(ah[ks], wh, acc[nt], 0, 0, 0);
            acc[nt] = __builtin_amdgcn_mfma_f32_16x16x32_bf16(ah[ks], wl, acc[nt], 0, 0, 0);
            acc[nt] = __builtin_amdgcn_mfma_f32_16x16x32_bf16(al[ks], wh, acc[nt], 0, 0, 0);
        }
    }

    // bias + hi/lo split -> LDS (C-layout: col=l16 chan-slice, row=quad*4+i)
#pragma unroll
    for (int nt = 0; nt < 4; nt++) {
        const int chan = nt * 16 + l16;
        const float bv = bias[chan];
#pragma unroll
        for (int i = 0; i < 4; i++) {
            const int rl = w * 16 + quad * 4 + i;        // local row 0..63
            const float e = acc[nt][i] + bv;
            const __hip_bfloat16 hi = __float2bfloat16(e);
            const __hip_bfloat16 lo = __float2bfloat16(e - __bfloat162float(hi));
            sEh[rl * 72 + chan] = hi;
            sEl[rl * 72 + chan] = lo;
            sEt[chan * 72 + rl] = hi;                    // transposed tile
        }
    }
    __syncthreads();

    // coalesced 16B stores
    const int bt = gr0 >> 11, ir0 = gr0 & (N_ - 1);
#pragma unroll
    for (int p = 0; p < 2; p++) {
        const int q = tid + p * 256;                     // 0..511
        const int r = q >> 3, c = (q & 7) * 8;
        *(uint4*)(e_hi + (size_t)(gr0 + r) * D_ + c)  = *(const uint4*)(sEh + r * 72 + c);
        *(uint4*)(e_lo + (size_t)(gr0 + r) * D_ + c)  = *(const uint4*)(sEl + r * 72 + c);
        *(uint4*)(e_hiT + ((size_t)bt * D_ + r) * N_ + ir0 + c) = *(const uint4*)(sEt + r * 72 + c);
    }
}

// ---------------------------------------------------------------------------
// Kernel 2: fused Gram(32x32x16, hi/lo split) + tanh/relu + direct lp store +
// PV(16x16x32) + nf. Grid (8 batches, 32 i-tiles of 64 rows) x 512 thr.
// Wave w = g2*4 + h2: Gram tile rows [i0+g2*32, +32), cols [j0+h2*32, +32).
// NO __syncthreads() in the j-loop: B-operands come straight from global
// (L2-resident, XCD-pinned by batch), sLp is a same-wave LDS transform.
// ---------------------------------------------------------------------------
#define LT 136   // sLp row stride (bf16 elems): 128+8 pad -> 272 B = 16 mod 128

__global__ __launch_bounds__(512) void fused_kernel(
    const __hip_bfloat16* __restrict__ e_hi,
    const __hip_bfloat16* __restrict__ e_lo,
    const __hip_bfloat16* __restrict__ e_hiT,
    float* __restrict__ out)
{
    __shared__ __align__(16) __hip_bfloat16 sLp[64 * LT];   // 17408 B
    __shared__ __align__(16) float sO[8 * 32 * 64];          // 65536 B

    const int b   = blockIdx.x;              // batch; linear%8==b -> XCD pin
    const int i0  = blockIdx.y * 64;
    const int tid = threadIdx.x;
    const int w = tid >> 6, lane = tid & 63;
    const int l32 = lane & 31, half = lane >> 5;
    const int quad = lane >> 4, l16 = lane & 15;
    const int g2 = w >> 2, h2 = w & 3;

    // Persistent Gram A-frags (32x32x16: m=l32, k=half*8+j), K=64 -> 4 ksteps
    const __hip_bfloat16* eih = e_hi + (size_t)(b * N_ + i0 + g2 * 32 + l32) * D_;
    const __hip_bfloat16* eil = e_lo + (size_t)(b * N_ + i0 + g2 * 32 + l32) * D_;
    bf16x8 ahi[4], alo[4];
#pragma unroll
    for (int ks = 0; ks < 4; ks++) {
        ahi[ks] = ld_frag(eih + ks * 16 + half * 8);
        alo[ks] = ld_frag(eil + ks * 16 + half * 8);
    }

    f32x4 o[2][4];
#pragma unroll
    for (int mt = 0; mt < 2; mt++)
#pragma unroll
        for (int nt = 0; nt < 4; nt++) o[mt][nt] = f32x4{0.f, 0.f, 0.f, 0.f};

    float* lp_out = out + (size_t)B_ * N_ * D_;

    for (int jt = 0; jt < 16; jt++) {
        const int j0 = jt * 128;

        // ---- Gram: S[32x32] = split product over K=64 ----
        const __hip_bfloat16* ejh = e_hi + (size_t)(b * N_ + j0 + h2 * 32 + l32) * D_;
        const __hip_bfloat16* ejl = e_lo + (size_t)(b * N_ + j0 + h2 * 32 + l32) * D_;
        f32x16 s = {};
#pragma unroll
        for (int ks = 0; ks < 4; ks++) {
            const bf16x8 bh = ld_frag(ejh + ks * 16 + half * 8);
            const bf16x8 bl = ld_frag(ejl + ks * 16 + half * 8);
            s = __builtin_amdgcn_mfma_f32_32x32x16_bf16(ahi[ks], bh, s, 0, 0, 0);
            s = __builtin_amdgcn_mfma_f32_32x32x16_bf16(ahi[ks], bl, s, 0, 0, 0);
            s = __builtin_amdgcn_mfma_f32_32x32x16_bf16(alo[ks], bh, s, 0, 0, 0);
        }

        // ---- activation -> direct lp store + sLp (same-wave transform) ----
        // C-layout 32x32: col=l32, row=(r&3)+8*(r>>2)+4*half
#pragma unroll
        for (int r = 0; r < 16; r++) {
            const int rl = (r & 3) + 8 * (r >> 2) + 4 * half;   // 0..31
            const float tc = fmaxf(s[r], 0.0f);
            const float z = __builtin_amdgcn_exp2f(tc * -2.8853900817779268f);
            const float v = (1.0f - z) * __builtin_amdgcn_rcpf(1.0f + z);
            lp_out[(size_t)(b * N_ + i0 + g2 * 32 + rl) * N_ + j0 + h2 * 32 + l32] = v;
            sLp[(g2 * 32 + rl) * LT + h2 * 32 + l32] = __float2bfloat16(v);
        }

        // drain own LDS writes before same-wave read (no barrier needed:
        // writer lanes and reader lanes are in the SAME wave by construction)
        __builtin_amdgcn_s_waitcnt(0xc07f);   // lgkmcnt(0)

        // ---- PV: O[32x64] += lp[32 x 32(h2)] @ E^T ----
#pragma unroll
        for (int mt = 0; mt < 2; mt++) {
            const bf16x8 a = ld_frag(sLp + (g2 * 32 + mt * 16 + l16) * LT + h2 * 32 + quad * 8);
#pragma unroll
            for (int nt = 0; nt < 4; nt++) {
                const bf16x8 bfr = ld_frag(e_hiT + ((size_t)b * D_ + nt * 16 + l16) * N_
                                           + j0 + h2 * 32 + quad * 8);
                o[mt][nt] = __builtin_amdgcn_mfma_f32_16x16x32_bf16(a, bfr, o[mt][nt], 0, 0, 0);
            }
        }
    }

    // ---- epilogue: reduce h2 partials, /N, store nf ----
    __syncthreads();   // first and only block-wide sync of the j-phase
#pragma unroll
    for (int mt = 0; mt < 2; mt++)
#pragma unroll
        for (int nt = 0; nt < 4; nt++)
#pragma unroll
            for (int i = 0; i < 4; i++)
                sO[w * 2048 + (mt * 16 + quad * 4 + i) * 64 + nt * 16 + l16] = o[mt][nt][i];
    __syncthreads();
#pragma unroll
    for (int p = 0; p < 8; p++) {
        const int q = tid + p * 512;          // 0..4095
        const int row = q >> 6, chan = q & 63;
        const int gg = row >> 5, rl = row & 31;
        float v = 0.f;
#pragma unroll
        for (int hh = 0; hh < 4; hh++)
            v += sO[(gg * 4 + hh) * 2048 + rl * 64 + chan];
        out[(size_t)(b * N_ + i0 + row) * D_ + chan] = v * (1.0f / 2048.0f);
    }
}

// ---------------------------------------------------------------------------
extern "C" void kernel_launch(void* const* d_in, const int* in_sizes, int n_in,
                              void* d_out, int out_size, void* d_ws, size_t ws_size,
                              hipStream_t stream) {
    const float* x    = (const float*)d_in[0];
    const float* W    = (const float*)d_in[1];
    const float* bias = (const float*)d_in[2];
    float* out = (float*)d_out;

    __hip_bfloat16* e_hi  = (__hip_bfloat16*)d_ws;            // [B*N][64]
    __hip_bfloat16* e_lo  = e_hi + (size_t)B_ * N_ * D_;
    __hip_bfloat16* e_hiT = e_lo + (size_t)B_ * N_ * D_;      // [B][64][N]
    __hip_bfloat16* whi   = e_hiT + (size_t)B_ * N_ * D_;     // [64][128]
    __hip_bfloat16* wlo   = whi + D_ * CIN_;

    wsplit_kernel<<<dim3(1), dim3(256), 0, stream>>>(W, whi, wlo);
    ex_kernel<<<dim3(256), dim3(256), 0, stream>>>(x, whi, wlo, bias, e_hi, e_lo, e_hiT);
    fused_kernel<<<dim3(8, 32), dim3(512), 0, stream>>>(e_hi, e_lo, e_hiT, out);
}